// Round 3
// baseline (697.123 us; speedup 1.0000x reference)
//
#include <hip/hip_runtime.h>

#define N_TOK 2048
#define B_SZ  8
#define E_DIM 256
#define H_DIM 512
#define KSPLIT 2
#define TPB   (N_TOK / 32 / KSPLIT)   // 32 key-tiles per block

typedef __attribute__((ext_vector_type(8))) short bf16x8;
typedef __attribute__((ext_vector_type(4))) float f32x4;
typedef __attribute__((ext_vector_type(4))) unsigned short u16x4;

__device__ __forceinline__ unsigned short f2bf(float f) {
    union { float f; unsigned u; } v; v.f = f;
    unsigned r = v.u + 0x7FFF + ((v.u >> 16) & 1);   // RNE
    return (unsigned short)(r >> 16);
}
__device__ __forceinline__ float bf2f(unsigned short b) {
    union { unsigned u; float f; } v; v.u = ((unsigned)b) << 16;
    return v.f;
}

// ---- Kernel 1: fused prep (vectorized, verified) ---------------------------
// blocks [0, 4096): row-normalize x -> Xn bf16 (B,N,E), 16B units XOR-swizzled
// blocks [4096, 12288): pack h (N,B,H) f32 -> Vp (B, N/32, H, 32) bf16, swizzled
// Also zeroes sumsq (block 0) so no separate memset dispatch is needed.
__global__ void prep_kernel(const float* __restrict__ x,
                            const float* __restrict__ hptr,
                            unsigned short* __restrict__ Xn,
                            unsigned short* __restrict__ Vp,
                            float* __restrict__ sumsq) {
    int bid = blockIdx.x;
    int t = threadIdx.x;
    if (bid == 0 && t == 0) *sumsq = 0.0f;
    if (bid < (N_TOK * B_SZ) / 4) {
        // ---- norm path: 4 rows/block, one per wave ----
        int w = t >> 6, lane = t & 63;
        int r = bid * 4 + w;                 // row in x memory order: r = n*B + b
        int n = r >> 3, b = r & 7;
        float4 v = *(const float4*)(x + (size_t)r * E_DIM + lane * 4);
        float s = v.x * v.x + v.y * v.y + v.z * v.z + v.w * v.w;
        #pragma unroll
        for (int o = 32; o > 0; o >>= 1) s += __shfl_xor(s, o);
        float rn = 1.0f / sqrtf(s);
        u16x4 pk;
        pk[0] = f2bf(v.x * rn); pk[1] = f2bf(v.y * rn);
        pk[2] = f2bf(v.z * rn); pk[3] = f2bf(v.w * rn);
        int u = lane >> 1, half = lane & 1;
        *(u16x4*)(Xn + ((size_t)b * N_TOK + n) * E_DIM
                     + (size_t)((u ^ (n & 7)) * 8 + half * 4)) = pk;
    } else {
        // ---- pack-V path ----
        int lin = bid - (N_TOK * B_SZ) / 4;    // 8192 blocks: (64, 16, 8)
        int jb = lin & 63, hb = (lin >> 6) & 15, b = lin >> 10;
        __shared__ float tile[32][33];
        int j0 = jb * 32, h0 = hb * 32;
        int tx = t & 31, ty = t >> 5;          // 32 x 8
        #pragma unroll
        for (int it = 0; it < 4; it++) {
            int j = j0 + ty + it * 8;
            tile[ty + it * 8][tx] = hptr[((size_t)j * B_SZ + b) * H_DIM + h0 + tx];
        }
        __syncthreads();
        size_t base = ((size_t)b * (N_TOK / 32) + jb) * (H_DIM * 32);
        int hcl = t >> 3, jg = (t >> 1) & 3, half = t & 1;
        int hc = h0 + hcl;
        u16x4 pk;
        #pragma unroll
        for (int k = 0; k < 4; k++)
            pk[k] = f2bf(tile[jg * 8 + half * 4 + k][hcl]);
        *(u16x4*)(Vp + base + (size_t)(hc * 4 + (jg ^ ((hcl >> 1) & 3))) * 8
                     + half * 4) = pk;
    }
}

// ---- Kernel 2: flash attention partial, grid split-K -----------------------
// Grid (8, 64, 2): z = key-half. Each block: 32 q-rows x 1024 keys (32 tiles).
// 1024 blocks -> 4 blocks/CU x 4 waves = 4 waves/SIMD (was 2): doubles the
// latency-hiding for the per-iter serial chain that round 2 proved dominant.
// Fixed-shift softmax (P = exp(s-1), scores in [-1,1]) => partials over
// disjoint key ranges are EXACTLY additive; z=0 writes its partial to `out`,
// z=1 to workspace, per-row l to Lpart. combine_kernel merges.
// Per wave: rg = w>>1 (16-q-row group), kh = w&1 (16-key half in QK^T AND
// 256-h-col half in PV); P shared across the kh pair via LDS + raw s_barrier.
#define PT_STRIDE 40   // shorts

__launch_bounds__(256, 4)
__global__ void flash_kernel(const unsigned short* __restrict__ Xn,
                             const unsigned short* __restrict__ Vp,
                             float* __restrict__ Op0,     // z=0 partial (= out)
                             float* __restrict__ Op1,     // z=1 partial (ws)
                             float* __restrict__ Lpart) { // [2][N*B]
    __shared__ __attribute__((aligned(16))) unsigned short Kbuf[2][32 * 256];
    __shared__ __attribute__((aligned(16))) unsigned short Pt[2][16 * PT_STRIDE];
    __shared__ float Lred[2][2][16];

    int b  = blockIdx.x;           // batch: linear-id % 8 == b -> XCD-pinned
    int q0 = blockIdx.y * 32;
    int z  = blockIdx.z;           // key-half
    int t = threadIdx.x;
    int w = t >> 6, lane = t & 63;
    int quad = lane >> 4, nm = lane & 15;
    int rg = w >> 1, kh = w & 1;   // kh doubles as PV col-half

    const unsigned short* Kbase = Xn + (size_t)b * N_TOK * E_DIM;
    const unsigned short* Qrow =
        Xn + ((size_t)b * N_TOK + q0 + rg * 16 + nm) * E_DIM;
    const unsigned short* Vtile0 = Vp + (size_t)b * (N_TOK / 32) * (H_DIM * 32);

    // Q fragments (swizzled layout: unit (ec*4+quad) ^ (row&7))
    bf16x8 qf[8];
    #pragma unroll
    for (int ec = 0; ec < 8; ec++)
        qf[ec] = *(const bf16x8*)(Qrow + (size_t)(((ec * 4 + quad) ^ (nm & 7)) * 8));

    f32x4 O[16];
    #pragma unroll
    for (int i = 0; i < 16; i++) O[i] = (f32x4){0.f, 0.f, 0.f, 0.f};
    float l_lane[4];
    #pragma unroll
    for (int r = 0; r < 4; r++) l_lane[r] = 0.0f;

    // K staging: 4 waves cooperatively copy the 16KB tile (swizzle pre-baked)
    auto stage = [&](int tile, int buf) {
        const unsigned short* src0 = Kbase + (size_t)tile * 32 * E_DIM;
        #pragma unroll
        for (int k = 0; k < 4; k++) {
            int chunk = w * 4 + k;                 // 0..15, 1KB each
            __builtin_amdgcn_global_load_lds(
                (const __attribute__((address_space(1))) unsigned int*)
                    (src0 + (size_t)chunk * 512 + lane * 8),
                (__attribute__((address_space(3))) unsigned int*)
                    (&Kbuf[buf][chunk * 512]),
                16, 0, 0);
        }
    };

    int tile0 = z * TPB;
    stage(tile0, 0);
    int vswz = (quad ^ ((nm >> 1) & 3)) * 8;
    int krow = kh * 16 + nm;       // the key row this wave computes in QK^T

    for (int ii = 0; ii < TPB; ++ii) {
        __syncthreads();                 // drains staging of current tile
        int cur = ii & 1;
        int it = tile0 + ii;

        // ---- V fragment prefetch (this iter), contiguous 1KB per instr ----
        const unsigned short* Vt = Vtile0 + (size_t)it * (H_DIM * 32);
        bf16x8 vf[16];
        #pragma unroll
        for (int tt = 0; tt < 16; tt++) {
            int hc = kh * 256 + tt * 16 + nm;
            vf[tt] = *(const bf16x8*)(Vt + (size_t)(hc * 4) * 8 + vswz);
        }

        if (ii + 1 < TPB) stage(it + 1, cur ^ 1);
        const unsigned short* KB = &Kbuf[cur][0];

        // ---- QK^T: 16 q-rows x 16 keys (this wave's half), K=256 ----
        f32x4 sa = (f32x4){0.f,0.f,0.f,0.f}, sb = (f32x4){0.f,0.f,0.f,0.f};
        #pragma unroll
        for (int ec = 0; ec < 4; ec++) {
            int u0 = (((2*ec)   * 4 + quad) ^ (nm & 7)) * 8;
            int u1 = (((2*ec+1) * 4 + quad) ^ (nm & 7)) * 8;
            bf16x8 kf0 = *(const bf16x8*)(KB + krow * 256 + u0);
            bf16x8 kf1 = *(const bf16x8*)(KB + krow * 256 + u1);
            sa = __builtin_amdgcn_mfma_f32_16x16x32_bf16(qf[2*ec],   kf0, sa, 0, 0, 0);
            sb = __builtin_amdgcn_mfma_f32_16x16x32_bf16(qf[2*ec+1], kf1, sb, 0, 0, 0);
        }

        // ---- fixed-shift softmax: P = exp(s-1), publish to shared Pt ----
        #pragma unroll
        for (int r = 0; r < 4; r++) {
            unsigned short pb = f2bf(__expf((sa[r] + sb[r]) - 1.0f));
            l_lane[r] += bf2f(pb);
            Pt[rg][(quad * 4 + r) * PT_STRIDE + kh * 16 + nm] = pb;
        }

        // raw barrier: waits DS only — staging/V loads stay in flight
        asm volatile("s_waitcnt lgkmcnt(0)" ::: "memory");
        __builtin_amdgcn_s_barrier();
        asm volatile("" ::: "memory");

        bf16x8 pf = *(const bf16x8*)(&Pt[rg][nm * PT_STRIDE + quad * 8]);

        // ---- PV (16 col-tiles x K=32) ----
        #pragma unroll
        for (int tt = 0; tt < 16; tt++)
            O[tt] = __builtin_amdgcn_mfma_f32_16x16x32_bf16(pf, vf[tt], O[tt], 0, 0, 0);
    }

    // ---- epilogue: per-row l over this block's keys, write partials ----
    float lv[4];
    #pragma unroll
    for (int r = 0; r < 4; r++) {
        float v = l_lane[r];
        #pragma unroll
        for (int o = 1; o < 16; o <<= 1) v += __shfl_xor(v, o);
        lv[r] = v;                         // sum over this wave's 16 keys
    }
    if (nm == 0) {
        #pragma unroll
        for (int r = 0; r < 4; r++) Lred[rg][kh][quad * 4 + r] = lv[r];
    }
    __syncthreads();
    if (t < 32) {
        int rgi = t >> 4, i = t & 15;
        Lpart[(size_t)z * (N_TOK * B_SZ) + (size_t)(q0 + t) * B_SZ + b] =
            Lred[rgi][0][i] + Lred[rgi][1][i];
    }

    float* Od = z ? Op1 : Op0;
    #pragma unroll
    for (int tt = 0; tt < 16; tt++) {
        #pragma unroll
        for (int r = 0; r < 4; r++) {
            int row = q0 + rg * 16 + quad * 4 + r;
            int col = kh * 256 + tt * 16 + nm;
            Od[((size_t)row * B_SZ + b) * H_DIM + col] = O[tt][r];
        }
    }
}

// ---- Kernel 3: combine partials, normalize rows, accumulate sumsq ----------
// out = (O0 + O1) / (l0 + l1); 2048 blocks x 256 thr x 4 float4 each.
__global__ void combine_kernel(float* __restrict__ out,       // Op0, in-place
                               const float* __restrict__ Op1,
                               const float* __restrict__ Lpart,
                               float* __restrict__ sumsq) {
    int t = threadIdx.x;
    float ss = 0.0f;
    #pragma unroll
    for (int p = 0; p < 4; p++) {
        size_t i4 = (size_t)blockIdx.x * 1024 + p * 256 + t;   // float4 index
        size_t g = i4 * 4;
        int r = (int)(g >> 9);                                 // row = n*B+b
        float linv = 1.0f / (Lpart[r] + Lpart[N_TOK * B_SZ + r]);
        float4 a = *(const float4*)(out + g);
        float4 c = *(const float4*)(Op1 + g);
        float4 v;
        v.x = (a.x + c.x) * linv; v.y = (a.y + c.y) * linv;
        v.z = (a.z + c.z) * linv; v.w = (a.w + c.w) * linv;
        *(float4*)(out + g) = v;
        ss += v.x * v.x + v.y * v.y + v.z * v.z + v.w * v.w;
    }
    #pragma unroll
    for (int o = 1; o < 64; o <<= 1) ss += __shfl_xor(ss, o);
    __shared__ float red[4];
    if ((t & 63) == 0) red[t >> 6] = ss;
    __syncthreads();
    if (t == 0) atomicAdd(sumsq, red[0] + red[1] + red[2] + red[3]);
}

// ---- Kernel 4: global-norm rescale ----------------------------------------
__global__ void scale_kernel(float* __restrict__ out,
                             const float* __restrict__ sumsq) {
    size_t idx = ((size_t)blockIdx.x * blockDim.x + threadIdx.x) * 4;
    float rs = 1.0f / sqrtf(*sumsq);
    float4 v = *(float4*)(out + idx);
    v.x *= rs; v.y *= rs; v.z *= rs; v.w *= rs;
    *(float4*)(out + idx) = v;
}

extern "C" void kernel_launch(void* const* d_in, const int* in_sizes, int n_in,
                              void* d_out, int out_size, void* d_ws, size_t ws_size,
                              hipStream_t stream) {
    const float* x = (const float*)d_in[0];
    const float* h = (const float*)d_in[1];
    float* out = (float*)d_out;

    unsigned short* Xn = (unsigned short*)d_ws;                   // 8.39 MB
    unsigned short* Vp = Xn + (size_t)B_SZ * N_TOK * E_DIM;       // 16.78 MB
    float* Op1 = (float*)(Vp + (size_t)B_SZ * N_TOK * H_DIM);     // 33.55 MB
    float* Lpart = Op1 + (size_t)N_TOK * B_SZ * H_DIM;            // 131 KB
    float* sumsq = Lpart + (size_t)KSPLIT * N_TOK * B_SZ;         // 4 B

    prep_kernel<<<(N_TOK * B_SZ) / 4 + (N_TOK / 32) * (H_DIM / 32) * B_SZ,
                  256, 0, stream>>>(x, h, Xn, Vp, sumsq);
    flash_kernel<<<dim3(B_SZ, N_TOK / 32, KSPLIT), 256, 0, stream>>>(
        Xn, Vp, out, Op1, Lpart);
    combine_kernel<<<(N_TOK * B_SZ * H_DIM) / (256 * 16), 256, 0, stream>>>(
        out, Op1, Lpart, sumsq);
    scale_kernel<<<out_size / (4 * 256), 256, 0, stream>>>(out, sumsq);
}

// Round 4
// 244.115 us; speedup vs baseline: 2.8557x; 2.8557x over previous
//
#include <hip/hip_runtime.h>

#define N_TOK 2048
#define B_SZ  8
#define E_DIM 256
#define H_DIM 512
#define ITERS (N_TOK / 32)     // 64

typedef __attribute__((ext_vector_type(8))) short bf16x8;
typedef __attribute__((ext_vector_type(4))) float f32x4;
typedef __attribute__((ext_vector_type(4))) unsigned short u16x4;

__device__ __forceinline__ unsigned short f2bf(float f) {
    union { float f; unsigned u; } v; v.f = f;
    unsigned r = v.u + 0x7FFF + ((v.u >> 16) & 1);   // RNE
    return (unsigned short)(r >> 16);
}
__device__ __forceinline__ float bf2f(unsigned short b) {
    union { unsigned u; float f; } v; v.u = ((unsigned)b) << 16;
    return v.f;
}

// ---- Kernel 1: fused prep (vectorized, verified) ---------------------------
// blocks [0, 4096): row-normalize x -> Xn bf16 (B,N,E), 16B units XOR-swizzled
// blocks [4096, 12288): pack h (N,B,H) f32 -> Vp (B, N/32, H, 32) bf16, swizzled
// Block 0 also zeroes sumsq (no separate memset dispatch).
__global__ void prep_kernel(const float* __restrict__ x,
                            const float* __restrict__ hptr,
                            unsigned short* __restrict__ Xn,
                            unsigned short* __restrict__ Vp,
                            float* __restrict__ sumsq) {
    int bid = blockIdx.x;
    int t = threadIdx.x;
    if (bid == 0 && t == 0) *sumsq = 0.0f;
    if (bid < (N_TOK * B_SZ) / 4) {
        // ---- norm path: 4 rows/block, one per wave ----
        int w = t >> 6, lane = t & 63;
        int r = bid * 4 + w;                 // row in x memory order: r = n*B + b
        int n = r >> 3, b = r & 7;
        float4 v = *(const float4*)(x + (size_t)r * E_DIM + lane * 4);
        float s = v.x * v.x + v.y * v.y + v.z * v.z + v.w * v.w;
        #pragma unroll
        for (int o = 32; o > 0; o >>= 1) s += __shfl_xor(s, o);
        float rn = 1.0f / sqrtf(s);
        u16x4 pk;
        pk[0] = f2bf(v.x * rn); pk[1] = f2bf(v.y * rn);
        pk[2] = f2bf(v.z * rn); pk[3] = f2bf(v.w * rn);
        int u = lane >> 1, half = lane & 1;
        *(u16x4*)(Xn + ((size_t)b * N_TOK + n) * E_DIM
                     + (size_t)((u ^ (n & 7)) * 8 + half * 4)) = pk;
    } else {
        // ---- pack-V path ----
        int lin = bid - (N_TOK * B_SZ) / 4;    // 8192 blocks: (64, 16, 8)
        int jb = lin & 63, hb = (lin >> 6) & 15, b = lin >> 10;
        __shared__ float tile[32][33];
        int j0 = jb * 32, h0 = hb * 32;
        int tx = t & 31, ty = t >> 5;          // 32 x 8
        #pragma unroll
        for (int it = 0; it < 4; it++) {
            int j = j0 + ty + it * 8;
            tile[ty + it * 8][tx] = hptr[((size_t)j * B_SZ + b) * H_DIM + h0 + tx];
        }
        __syncthreads();
        size_t base = ((size_t)b * (N_TOK / 32) + jb) * (H_DIM * 32);
        int hcl = t >> 3, jg = (t >> 1) & 3, half = t & 1;
        int hc = h0 + hcl;
        u16x4 pk;
        #pragma unroll
        for (int k = 0; k < 4; k++)
            pk[k] = f2bf(tile[jg * 8 + half * 4 + k][hcl]);
        *(u16x4*)(Vp + base + (size_t)(hc * 4 + (jg ^ ((hcl >> 1) & 3))) * 8
                     + half * 4) = pk;
    }
}

// ---- Kernel 2: fused flash attention, 8-wave low-register form -------------
// The round-1/3 lesson: per-wave state must fit 128 regs (arch+acc combined)
// to reach 4 waves/SIMD. 512 threads, 8 waves, per-wave arrays HALVED:
//   es = w&1     : E-half of QK^T  (qf[4] = 16 regs, 4 MFMAs, K=128 partial)
//   kh = (w>>1)&1: 16-key half of the 32-key tile
//   rg = w>>2    : 16-q-row group
//   pc = w&3     : 128-h-col quarter in PV (vf[8]=32, O[8]=32 regs)
// es-partials of the scores are exchanged via LDS (Spart) + raw s_barrier;
// es==0 does exp(s-1) and publishes P to Pt; second raw s_barrier; PV.
// Fixed-shift softmax: scores are cosine sims in [-1,1] -> P = exp(s-1),
// no max, no rescale. Grid (8,64) = 512 blocks = 2 blocks/CU x 8 waves
// = 4 waves/SIMD (2x round 2). Live state ~112 regs -> no spill at the
// (512,4) cap. LDS 43.8 KB -> 2 blocks/CU fits.
#define PT_STRIDE 40   // shorts

__launch_bounds__(512, 4)
__global__ void flash_kernel(const unsigned short* __restrict__ Xn,
                             const unsigned short* __restrict__ Vp,
                             float* __restrict__ out,
                             float* __restrict__ sumsq) {
    __shared__ __attribute__((aligned(16))) unsigned short Kbuf[2][32 * 256];
    __shared__ __attribute__((aligned(16))) unsigned short Pt[2][16 * PT_STRIDE];
    __shared__ __attribute__((aligned(16))) float Spart[8][256];
    __shared__ float Lred[2][2][16];

    int b  = blockIdx.x;           // batch: linear-id % 8 == b -> XCD-pinned
    int q0 = blockIdx.y * 32;
    int t = threadIdx.x;
    int w = t >> 6, lane = t & 63;
    int quad = lane >> 4, nm = lane & 15;
    int es = w & 1, kh = (w >> 1) & 1, rg = w >> 2, pc = w & 3;

    const unsigned short* Kbase = Xn + (size_t)b * N_TOK * E_DIM;
    const unsigned short* Qrow =
        Xn + ((size_t)b * N_TOK + q0 + rg * 16 + nm) * E_DIM;
    const unsigned short* Vtile0 = Vp + (size_t)b * (N_TOK / 32) * (H_DIM * 32);

    // Q fragments for this wave's E-half (swizzled: unit (ec*4+quad)^(row&7))
    bf16x8 qf[4];
    #pragma unroll
    for (int j = 0; j < 4; j++) {
        int ec = es * 4 + j;
        qf[j] = *(const bf16x8*)(Qrow + (size_t)(((ec * 4 + quad) ^ (nm & 7)) * 8));
    }

    f32x4 O[8];
    #pragma unroll
    for (int i = 0; i < 8; i++) O[i] = (f32x4){0.f, 0.f, 0.f, 0.f};
    float l_lane[4];
    #pragma unroll
    for (int r = 0; r < 4; r++) l_lane[r] = 0.0f;

    // K staging: 8 waves x 2 chunks of 1KB = 16KB tile (swizzle pre-baked)
    auto stage = [&](int tile, int buf) {
        const unsigned short* src0 = Kbase + (size_t)tile * 32 * E_DIM;
        #pragma unroll
        for (int k = 0; k < 2; k++) {
            int chunk = w * 2 + k;                 // 0..15, 1KB each
            __builtin_amdgcn_global_load_lds(
                (const __attribute__((address_space(1))) unsigned int*)
                    (src0 + (size_t)chunk * 512 + lane * 8),
                (__attribute__((address_space(3))) unsigned int*)
                    (&Kbuf[buf][chunk * 512]),
                16, 0, 0);
        }
    };

    stage(0, 0);
    int vswz = (quad ^ ((nm >> 1) & 3)) * 8;
    int krow = kh * 16 + nm;       // the key row this wave computes in QK^T

    for (int it = 0; it < ITERS; ++it) {
        __syncthreads();                 // drains staging of tile `it`
        int cur = it & 1;

        // ---- V fragment prefetch (this iter): 8 tiles of this pc quarter ----
        const unsigned short* Vt = Vtile0 + (size_t)it * (H_DIM * 32);
        bf16x8 vf[8];
        #pragma unroll
        for (int tt = 0; tt < 8; tt++) {
            int hc = pc * 128 + tt * 16 + nm;
            vf[tt] = *(const bf16x8*)(Vt + (size_t)(hc * 4) * 8 + vswz);
        }

        if (it + 1 < ITERS) stage(it + 1, cur ^ 1);
        const unsigned short* KB = &Kbuf[cur][0];

        // ---- QK^T partial: 16 q-rows x 16 keys, this wave's K=128 half ----
        f32x4 s = (f32x4){0.f, 0.f, 0.f, 0.f};
        #pragma unroll
        for (int j = 0; j < 4; j++) {
            int ec = es * 4 + j;
            int u = ((ec * 4 + quad) ^ (nm & 7)) * 8;
            bf16x8 kf = *(const bf16x8*)(KB + krow * 256 + u);
            s = __builtin_amdgcn_mfma_f32_16x16x32_bf16(qf[j], kf, s, 0, 0, 0);
        }

        // ---- exchange es-partials via LDS, raw barrier (no vmcnt drain) ----
        *(f32x4*)(&Spart[w][lane * 4]) = s;
        asm volatile("s_waitcnt lgkmcnt(0)" ::: "memory");
        __builtin_amdgcn_s_barrier();
        asm volatile("" ::: "memory");

        if (es == 0) {
            f32x4 s2 = *(const f32x4*)(&Spart[w ^ 1][lane * 4]);
            #pragma unroll
            for (int r = 0; r < 4; r++) {
                unsigned short pb = f2bf(__expf((s[r] + s2[r]) - 1.0f));
                l_lane[r] += bf2f(pb);
                Pt[rg][(quad * 4 + r) * PT_STRIDE + kh * 16 + nm] = pb;
            }
        }

        asm volatile("s_waitcnt lgkmcnt(0)" ::: "memory");
        __builtin_amdgcn_s_barrier();
        asm volatile("" ::: "memory");

        bf16x8 pf = *(const bf16x8*)(&Pt[rg][nm * PT_STRIDE + quad * 8]);

        // ---- PV (8 col-tiles x K=32) ----
        #pragma unroll
        for (int tt = 0; tt < 8; tt++)
            O[tt] = __builtin_amdgcn_mfma_f32_16x16x32_bf16(pf, vf[tt], O[tt], 0, 0, 0);
    }

    // ---- epilogue: l reduction (es==0 waves own it), normalize, write ----
    if (es == 0) {
        float lv[4];
        #pragma unroll
        for (int r = 0; r < 4; r++) {
            float v = l_lane[r];
            #pragma unroll
            for (int o = 1; o < 16; o <<= 1) v += __shfl_xor(v, o);
            lv[r] = v;                     // sum over this wave's 16 keys
        }
        if (nm == 0) {
            #pragma unroll
            for (int r = 0; r < 4; r++) Lred[rg][kh][quad * 4 + r] = lv[r];
        }
    }
    __syncthreads();
    float linv[4];
    #pragma unroll
    for (int r = 0; r < 4; r++)
        linv[r] = 1.0f / (Lred[rg][0][quad * 4 + r] + Lred[rg][1][quad * 4 + r]);

    float ss = 0.0f;
    #pragma unroll
    for (int tt = 0; tt < 8; tt++) {
        #pragma unroll
        for (int r = 0; r < 4; r++) {
            float val = O[tt][r] * linv[r];
            int row = q0 + rg * 16 + quad * 4 + r;
            int col = pc * 128 + tt * 16 + nm;
            out[((size_t)row * B_SZ + b) * H_DIM + col] = val;
            ss += val * val;
        }
    }
    #pragma unroll
    for (int o = 1; o < 64; o <<= 1) ss += __shfl_xor(ss, o);
    if (lane == 0) atomicAdd(sumsq, ss);
}

// ---- Kernel 3: global-norm rescale ----------------------------------------
__global__ void scale_kernel(float* __restrict__ out,
                             const float* __restrict__ sumsq) {
    size_t idx = ((size_t)blockIdx.x * blockDim.x + threadIdx.x) * 4;
    float rs = 1.0f / sqrtf(*sumsq);
    float4 v = *(float4*)(out + idx);
    v.x *= rs; v.y *= rs; v.z *= rs; v.w *= rs;
    *(float4*)(out + idx) = v;
}

extern "C" void kernel_launch(void* const* d_in, const int* in_sizes, int n_in,
                              void* d_out, int out_size, void* d_ws, size_t ws_size,
                              hipStream_t stream) {
    const float* x = (const float*)d_in[0];
    const float* h = (const float*)d_in[1];
    float* out = (float*)d_out;

    unsigned short* Xn = (unsigned short*)d_ws;                  // 8.39 MB
    unsigned short* Vp = Xn + (size_t)B_SZ * N_TOK * E_DIM;      // 16.78 MB
    float* sumsq = (float*)(Vp + (size_t)B_SZ * N_TOK * H_DIM);  // 4 B

    prep_kernel<<<(N_TOK * B_SZ) / 4 + (N_TOK / 32) * (H_DIM / 32) * B_SZ,
                  256, 0, stream>>>(x, h, Xn, Vp, sumsq);
    flash_kernel<<<dim3(B_SZ, N_TOK / 32), 512, 0, stream>>>(Xn, Vp, out, sumsq);
    scale_kernel<<<out_size / (4 * 256), 256, 0, stream>>>(out, sumsq);
}

// Round 5
// 243.123 us; speedup vs baseline: 2.8674x; 1.0041x over previous
//
#include <hip/hip_runtime.h>

#define N_TOK 2048
#define B_SZ  8
#define E_DIM 256
#define H_DIM 512
#define KSPLIT 2
#define TPB   (N_TOK / 32 / KSPLIT)   // 32 key-tiles per block

typedef __attribute__((ext_vector_type(8))) short bf16x8;
typedef __attribute__((ext_vector_type(4))) float f32x4;
typedef __attribute__((ext_vector_type(4))) unsigned short u16x4;

__device__ __forceinline__ unsigned short f2bf(float f) {
    union { float f; unsigned u; } v; v.f = f;
    unsigned r = v.u + 0x7FFF + ((v.u >> 16) & 1);   // RNE
    return (unsigned short)(r >> 16);
}
__device__ __forceinline__ float bf2f(unsigned short b) {
    union { unsigned u; float f; } v; v.u = ((unsigned)b) << 16;
    return v.f;
}

// ---- Kernel 1: fused prep (vectorized, verified) ---------------------------
// blocks [0, 4096): row-normalize x -> Xn bf16 (B,N,E), 16B units XOR-swizzled
// blocks [4096, 12288): pack h (N,B,H) f32 -> Vp (B, N/32, H, 32) bf16, swizzled
// Block 0 also zeroes sumsq (no separate memset dispatch).
__global__ void prep_kernel(const float* __restrict__ x,
                            const float* __restrict__ hptr,
                            unsigned short* __restrict__ Xn,
                            unsigned short* __restrict__ Vp,
                            float* __restrict__ sumsq) {
    int bid = blockIdx.x;
    int t = threadIdx.x;
    if (bid == 0 && t == 0) *sumsq = 0.0f;
    if (bid < (N_TOK * B_SZ) / 4) {
        // ---- norm path: 4 rows/block, one per wave ----
        int w = t >> 6, lane = t & 63;
        int r = bid * 4 + w;                 // row in x memory order: r = n*B + b
        int n = r >> 3, b = r & 7;
        float4 v = *(const float4*)(x + (size_t)r * E_DIM + lane * 4);
        float s = v.x * v.x + v.y * v.y + v.z * v.z + v.w * v.w;
        #pragma unroll
        for (int o = 32; o > 0; o >>= 1) s += __shfl_xor(s, o);
        float rn = 1.0f / sqrtf(s);
        u16x4 pk;
        pk[0] = f2bf(v.x * rn); pk[1] = f2bf(v.y * rn);
        pk[2] = f2bf(v.z * rn); pk[3] = f2bf(v.w * rn);
        int u = lane >> 1, half = lane & 1;
        *(u16x4*)(Xn + ((size_t)b * N_TOK + n) * E_DIM
                     + (size_t)((u ^ (n & 7)) * 8 + half * 4)) = pk;
    } else {
        // ---- pack-V path ----
        int lin = bid - (N_TOK * B_SZ) / 4;    // 8192 blocks: (64, 16, 8)
        int jb = lin & 63, hb = (lin >> 6) & 15, b = lin >> 10;
        __shared__ float tile[32][33];
        int j0 = jb * 32, h0 = hb * 32;
        int tx = t & 31, ty = t >> 5;          // 32 x 8
        #pragma unroll
        for (int it = 0; it < 4; it++) {
            int j = j0 + ty + it * 8;
            tile[ty + it * 8][tx] = hptr[((size_t)j * B_SZ + b) * H_DIM + h0 + tx];
        }
        __syncthreads();
        size_t base = ((size_t)b * (N_TOK / 32) + jb) * (H_DIM * 32);
        int hcl = t >> 3, jg = (t >> 1) & 3, half = t & 1;
        int hc = h0 + hcl;
        u16x4 pk;
        #pragma unroll
        for (int k = 0; k < 4; k++)
            pk[k] = f2bf(tile[jg * 8 + half * 4 + k][hcl]);
        *(u16x4*)(Vp + base + (size_t)(hc * 4 + (jg ^ ((hcl >> 1) & 3))) * 8
                     + half * 4) = pk;
    }
}

// ---- Kernel 2: flash attention partial, grid split-K -----------------------
// ROUND-5 = round 3 with the spill removed. The round-2 4-wave body (proven
// VGPR=116, no spill, shortest per-iter chain: 2 barriers) + grid (8,64,2).
// 1024 blocks -> 4 INDEPENDENT blocks/CU (round-4 lesson: intra-block waves
// are barrier-locked; only independent blocks hide the per-iter latency
// chain). __launch_bounds__(256, 2): reg cap 256, actual 116 <= 128 so the
// hardware can run 4 waves/SIMD; no (.,4) forced-spill (round-3 bug).
// Fixed-shift softmax (P = exp(s-1), scores in [-1,1]) => partials over
// disjoint key ranges are EXACTLY additive; z=0 -> out, z=1 -> ws, l -> Lpart.
#define PT_STRIDE 40   // shorts

__launch_bounds__(256, 2)
__global__ void flash_kernel(const unsigned short* __restrict__ Xn,
                             const unsigned short* __restrict__ Vp,
                             float* __restrict__ Op0,     // z=0 partial (= out)
                             float* __restrict__ Op1,     // z=1 partial (ws)
                             float* __restrict__ Lpart) { // [2][N*B]
    __shared__ __attribute__((aligned(16))) unsigned short Kbuf[2][32 * 256];
    __shared__ __attribute__((aligned(16))) unsigned short Pt[2][16 * PT_STRIDE];
    __shared__ float Lred[2][2][16];

    int b  = blockIdx.x;           // batch: linear-id % 8 == b -> XCD-pinned
    int q0 = blockIdx.y * 32;
    int z  = blockIdx.z;           // key-half
    int t = threadIdx.x;
    int w = t >> 6, lane = t & 63;
    int quad = lane >> 4, nm = lane & 15;
    int rg = w >> 1, kh = w & 1;   // kh doubles as PV col-half

    const unsigned short* Kbase = Xn + (size_t)b * N_TOK * E_DIM;
    const unsigned short* Qrow =
        Xn + ((size_t)b * N_TOK + q0 + rg * 16 + nm) * E_DIM;
    const unsigned short* Vtile0 = Vp + (size_t)b * (N_TOK / 32) * (H_DIM * 32);

    // Q fragments (swizzled layout: unit (ec*4+quad) ^ (row&7))
    bf16x8 qf[8];
    #pragma unroll
    for (int ec = 0; ec < 8; ec++)
        qf[ec] = *(const bf16x8*)(Qrow + (size_t)(((ec * 4 + quad) ^ (nm & 7)) * 8));

    f32x4 O[16];
    #pragma unroll
    for (int i = 0; i < 16; i++) O[i] = (f32x4){0.f, 0.f, 0.f, 0.f};
    float l_lane[4];
    #pragma unroll
    for (int r = 0; r < 4; r++) l_lane[r] = 0.0f;

    // K staging: 4 waves cooperatively copy the 16KB tile (swizzle pre-baked)
    auto stage = [&](int tile, int buf) {
        const unsigned short* src0 = Kbase + (size_t)tile * 32 * E_DIM;
        #pragma unroll
        for (int k = 0; k < 4; k++) {
            int chunk = w * 4 + k;                 // 0..15, 1KB each
            __builtin_amdgcn_global_load_lds(
                (const __attribute__((address_space(1))) unsigned int*)
                    (src0 + (size_t)chunk * 512 + lane * 8),
                (__attribute__((address_space(3))) unsigned int*)
                    (&Kbuf[buf][chunk * 512]),
                16, 0, 0);
        }
    };

    int tile0 = z * TPB;
    stage(tile0, 0);
    int vswz = (quad ^ ((nm >> 1) & 3)) * 8;
    int krow = kh * 16 + nm;       // the key row this wave computes in QK^T

    for (int ii = 0; ii < TPB; ++ii) {
        __syncthreads();                 // drains staging of current tile
        int cur = ii & 1;
        int it = tile0 + ii;

        // ---- V fragment prefetch (this iter), contiguous 1KB per instr ----
        const unsigned short* Vt = Vtile0 + (size_t)it * (H_DIM * 32);
        bf16x8 vf[16];
        #pragma unroll
        for (int tt = 0; tt < 16; tt++) {
            int hc = kh * 256 + tt * 16 + nm;
            vf[tt] = *(const bf16x8*)(Vt + (size_t)(hc * 4) * 8 + vswz);
        }

        if (ii + 1 < TPB) stage(it + 1, cur ^ 1);
        const unsigned short* KB = &Kbuf[cur][0];

        // ---- QK^T: 16 q-rows x 16 keys (this wave's half), K=256 ----
        f32x4 sa = (f32x4){0.f,0.f,0.f,0.f}, sb = (f32x4){0.f,0.f,0.f,0.f};
        #pragma unroll
        for (int ec = 0; ec < 4; ec++) {
            int u0 = (((2*ec)   * 4 + quad) ^ (nm & 7)) * 8;
            int u1 = (((2*ec+1) * 4 + quad) ^ (nm & 7)) * 8;
            bf16x8 kf0 = *(const bf16x8*)(KB + krow * 256 + u0);
            bf16x8 kf1 = *(const bf16x8*)(KB + krow * 256 + u1);
            sa = __builtin_amdgcn_mfma_f32_16x16x32_bf16(qf[2*ec],   kf0, sa, 0, 0, 0);
            sb = __builtin_amdgcn_mfma_f32_16x16x32_bf16(qf[2*ec+1], kf1, sb, 0, 0, 0);
        }

        // ---- fixed-shift softmax: P = exp(s-1), publish to shared Pt ----
        #pragma unroll
        for (int r = 0; r < 4; r++) {
            unsigned short pb = f2bf(__expf((sa[r] + sb[r]) - 1.0f));
            l_lane[r] += bf2f(pb);
            Pt[rg][(quad * 4 + r) * PT_STRIDE + kh * 16 + nm] = pb;
        }

        // raw barrier: waits DS only — staging/V loads stay in flight
        asm volatile("s_waitcnt lgkmcnt(0)" ::: "memory");
        __builtin_amdgcn_s_barrier();
        asm volatile("" ::: "memory");

        bf16x8 pf = *(const bf16x8*)(&Pt[rg][nm * PT_STRIDE + quad * 8]);

        // ---- PV (16 col-tiles x K=32) ----
        #pragma unroll
        for (int tt = 0; tt < 16; tt++)
            O[tt] = __builtin_amdgcn_mfma_f32_16x16x32_bf16(pf, vf[tt], O[tt], 0, 0, 0);
    }

    // ---- epilogue: per-row l over this block's keys, write partials ----
    float lv[4];
    #pragma unroll
    for (int r = 0; r < 4; r++) {
        float v = l_lane[r];
        #pragma unroll
        for (int o = 1; o < 16; o <<= 1) v += __shfl_xor(v, o);
        lv[r] = v;                         // sum over this wave's 16 keys
    }
    if (nm == 0) {
        #pragma unroll
        for (int r = 0; r < 4; r++) Lred[rg][kh][quad * 4 + r] = lv[r];
    }
    __syncthreads();
    if (t < 32) {
        int rgi = t >> 4, i = t & 15;
        Lpart[(size_t)z * (N_TOK * B_SZ) + (size_t)(q0 + t) * B_SZ + b] =
            Lred[rgi][0][i] + Lred[rgi][1][i];
    }

    float* Od = z ? Op1 : Op0;
    #pragma unroll
    for (int tt = 0; tt < 16; tt++) {
        #pragma unroll
        for (int r = 0; r < 4; r++) {
            int row = q0 + rg * 16 + quad * 4 + r;
            int col = kh * 256 + tt * 16 + nm;
            Od[((size_t)row * B_SZ + b) * H_DIM + col] = O[tt][r];
        }
    }
}

// ---- Kernel 3: combine partials, normalize rows, accumulate sumsq ----------
// out = (O0 + O1) / (l0 + l1); 2048 blocks x 256 thr x 4 float4 each.
__global__ void combine_kernel(float* __restrict__ out,       // Op0, in-place
                               const float* __restrict__ Op1,
                               const float* __restrict__ Lpart,
                               float* __restrict__ sumsq) {
    int t = threadIdx.x;
    float ss = 0.0f;
    #pragma unroll
    for (int p = 0; p < 4; p++) {
        size_t i4 = (size_t)blockIdx.x * 1024 + p * 256 + t;   // float4 index
        size_t g = i4 * 4;
        int r = (int)(g >> 9);                                 // row = n*B+b
        float linv = 1.0f / (Lpart[r] + Lpart[N_TOK * B_SZ + r]);
        float4 a = *(const float4*)(out + g);
        float4 c = *(const float4*)(Op1 + g);
        float4 v;
        v.x = (a.x + c.x) * linv; v.y = (a.y + c.y) * linv;
        v.z = (a.z + c.z) * linv; v.w = (a.w + c.w) * linv;
        *(float4*)(out + g) = v;
        ss += v.x * v.x + v.y * v.y + v.z * v.z + v.w * v.w;
    }
    #pragma unroll
    for (int o = 1; o < 64; o <<= 1) ss += __shfl_xor(ss, o);
    __shared__ float red[4];
    if ((t & 63) == 0) red[t >> 6] = ss;
    __syncthreads();
    if (t == 0) atomicAdd(sumsq, red[0] + red[1] + red[2] + red[3]);
}

// ---- Kernel 4: global-norm rescale ----------------------------------------
__global__ void scale_kernel(float* __restrict__ out,
                             const float* __restrict__ sumsq) {
    size_t idx = ((size_t)blockIdx.x * blockDim.x + threadIdx.x) * 4;
    float rs = 1.0f / sqrtf(*sumsq);
    float4 v = *(float4*)(out + idx);
    v.x *= rs; v.y *= rs; v.z *= rs; v.w *= rs;
    *(float4*)(out + idx) = v;
}

extern "C" void kernel_launch(void* const* d_in, const int* in_sizes, int n_in,
                              void* d_out, int out_size, void* d_ws, size_t ws_size,
                              hipStream_t stream) {
    const float* x = (const float*)d_in[0];
    const float* h = (const float*)d_in[1];
    float* out = (float*)d_out;

    unsigned short* Xn = (unsigned short*)d_ws;                   // 8.39 MB
    unsigned short* Vp = Xn + (size_t)B_SZ * N_TOK * E_DIM;       // 16.78 MB
    float* Op1 = (float*)(Vp + (size_t)B_SZ * N_TOK * H_DIM);     // 33.55 MB
    float* Lpart = Op1 + (size_t)N_TOK * B_SZ * H_DIM;            // 131 KB
    float* sumsq = Lpart + (size_t)KSPLIT * N_TOK * B_SZ;         // 4 B

    prep_kernel<<<(N_TOK * B_SZ) / 4 + (N_TOK / 32) * (H_DIM / 32) * B_SZ,
                  256, 0, stream>>>(x, h, Xn, Vp, sumsq);
    flash_kernel<<<dim3(B_SZ, N_TOK / 32, KSPLIT), 256, 0, stream>>>(
        Xn, Vp, out, Op1, Lpart);
    combine_kernel<<<(N_TOK * B_SZ * H_DIM) / (256 * 16), 256, 0, stream>>>(
        out, Op1, Lpart, sumsq);
    scale_kernel<<<out_size / (4 * 256), 256, 0, stream>>>(out, sumsq);
}